// Round 1
// baseline (24.582 us; speedup 1.0000x reference)
//
#include <hip/hip_runtime.h>

// RadiusGraphLayer: dist[i,j] = ||pos_i - pos_j|| if (same graph, i!=j, d<=5), else 0
// mask[i,j] = 1.0/0.0. Outputs concatenated: d_out[0..N^2) = dist, d_out[N^2..2N^2) = mask.
// N=4096, 8 graphs x 512 atoms. Write-BW-bound: 134 MB of output.

#define NATOMS 4096
#define QPR    1024            // quads (float4) per row = N/4
#define CUTOFF2 25.0f

__global__ __launch_bounds__(256) void radius_graph_kernel(
    const float* __restrict__ pos,
    const int*   __restrict__ batch,
    float*       __restrict__ dist,
    float*       __restrict__ mask)
{
    const long long total  = (long long)NATOMS * QPR;   // 4,194,304 float4 slots per output
    const long long stride = (long long)gridDim.x * blockDim.x;

    for (long long idx = (long long)blockIdx.x * blockDim.x + threadIdx.x;
         idx < total; idx += stride) {

        const int i  = (int)(idx >> 10);          // row
        const int j0 = ((int)idx & 1023) << 2;    // first col of this quad
        const long long off = ((long long)i << 12) + j0;

        float4 dv, mv;

        // batch is monotone; a 4-wide quad never straddles a 512 boundary.
        if (batch[i] != batch[j0]) {
            dv = make_float4(0.f, 0.f, 0.f, 0.f);
            mv = dv;
        } else {
            const float xi = pos[i * 3 + 0];
            const float yi = pos[i * 3 + 1];
            const float zi = pos[i * 3 + 2];

            // 12 contiguous floats at 16B-aligned offset (j0 % 4 == 0 -> 48B offset)
            const float4* pj = (const float4*)(pos + (long long)j0 * 3);
            const float4 p0 = pj[0];
            const float4 p1 = pj[1];
            const float4 p2 = pj[2];

            const float xj[4] = {p0.x, p0.w, p1.z, p2.y};
            const float yj[4] = {p0.y, p1.x, p1.w, p2.z};
            const float zj[4] = {p0.z, p1.y, p2.x, p2.w};

            float d[4], m[4];
            #pragma unroll
            for (int k = 0; k < 4; ++k) {
                // Match numpy f32 exactly: no FMA contraction on the d2 path,
                // so the d2 <= 25.0 boundary decision agrees bit-for-bit.
                const float dx = __fsub_rn(xi, xj[k]);
                const float dy = __fsub_rn(yi, yj[k]);
                const float dz = __fsub_rn(zi, zj[k]);
                const float d2 = __fadd_rn(
                    __fadd_rn(__fmul_rn(dx, dx), __fmul_rn(dy, dy)),
                    __fmul_rn(dz, dz));
                const bool me = (i != (j0 + k)) && (d2 <= CUTOFF2);
                m[k] = me ? 1.0f : 0.0f;
                d[k] = me ? sqrtf(d2) : 0.0f;
            }
            dv = make_float4(d[0], d[1], d[2], d[3]);
            mv = make_float4(m[0], m[1], m[2], m[3]);
        }

        *(float4*)(dist + off) = dv;
        *(float4*)(mask + off) = mv;
    }
}

extern "C" void kernel_launch(void* const* d_in, const int* in_sizes, int n_in,
                              void* d_out, int out_size, void* d_ws, size_t ws_size,
                              hipStream_t stream)
{
    const float* pos   = (const float*)d_in[0];
    const int*   batch = (const int*)d_in[1];
    float* dist = (float*)d_out;
    float* mask = (float*)d_out + (long long)NATOMS * NATOMS;

    const int threads = 256;
    const int blocks  = 2048;   // grid-stride, ~8 iters/thread; 256 CUs x 8 blocks
    radius_graph_kernel<<<blocks, threads, 0, stream>>>(pos, batch, dist, mask);
}